// Round 1
// baseline (11523.470 us; speedup 1.0000x reference)
//
#include <hip/hip_runtime.h>
#include <hip/hip_bf16.h>
#include <math.h>

// Problem constants (from reference)
#define NLAYERS 6
#define HEADS   16
#define CDIM    1024
#define HDIM    64
#define VOCAB   32000
#define TSEQ    1024
#define BATCH   2
#define ROWS    (BATCH*TSEQ)   // 2048
#define DFFDIM  4096

typedef __attribute__((ext_vector_type(8))) short  short8;
typedef __attribute__((ext_vector_type(4))) float  floatx4;

__device__ __forceinline__ short f2bs(float f) {
    __hip_bfloat16 h = __float2bfloat16(f);
    return *reinterpret_cast<short*>(&h);
}

// ---------------------------------------------------------------- embedding
__global__ __launch_bounds__(256) void embed_kernel(
    const int* __restrict__ idx, const float* __restrict__ wte,
    const float* __restrict__ wpe, float* __restrict__ x)
{
    int r = blockIdx.x;             // 0..2047
    int tok = idx[r];
    int pos = r & (TSEQ - 1);
    const float4* a = (const float4*)(wte + (size_t)tok * CDIM);
    const float4* p = (const float4*)(wpe + (size_t)pos * CDIM);
    float4* o = (float4*)(x + (size_t)r * CDIM);
    int t = threadIdx.x;            // CDIM/4 == 256
    float4 av = a[t], pv = p[t];
    o[t] = make_float4(av.x + pv.x, av.y + pv.y, av.z + pv.z, av.w + pv.w);
}

// ---------------------------------------------------------------- layernorm
__global__ __launch_bounds__(256) void ln_kernel(
    const float* __restrict__ x, const float* __restrict__ g,
    const float* __restrict__ b, __hip_bfloat16* __restrict__ out)
{
    int r = blockIdx.x;
    int t = threadIdx.x;
    const float* xr = x + (size_t)r * CDIM;
    float v[4];
#pragma unroll
    for (int i = 0; i < 4; i++) v[i] = xr[t + i * 256];

    __shared__ float red[4];
    int w = t >> 6, lane = t & 63;

    float s = v[0] + v[1] + v[2] + v[3];
    for (int off = 32; off; off >>= 1) s += __shfl_xor(s, off);
    if (lane == 0) red[w] = s;
    __syncthreads();
    float mean = (red[0] + red[1] + red[2] + red[3]) * (1.0f / CDIM);

    float s2 = 0.0f;
#pragma unroll
    for (int i = 0; i < 4; i++) { float d = v[i] - mean; s2 += d * d; }
    for (int off = 32; off; off >>= 1) s2 += __shfl_xor(s2, off);
    __syncthreads();
    if (lane == 0) red[w] = s2;
    __syncthreads();
    float var = (red[0] + red[1] + red[2] + red[3]) * (1.0f / CDIM);
    float rstd = rsqrtf(var + 1e-5f);

#pragma unroll
    for (int i = 0; i < 4; i++) {
        int c = t + i * 256;
        out[(size_t)r * CDIM + c] =
            __float2bfloat16((v[i] - mean) * rstd * g[c] + b[c]);
    }
}

// ---------------------------------------------------------------- GEMM
// C[M,N] = A[M,K](bf16) @ B (fp32 weights, cast to bf16 in staging)
// BNT=false: B is [K,N] row-major.  BNT=true: B is [N,K] row-major.
// Epilogue: +bias, gelu(exact), +resid (fp32), store fp32 (Cf) or bf16 (Cb).
template <bool BNT>
__global__ __launch_bounds__(256) void gemm_kernel(
    const __hip_bfloat16* __restrict__ A, const float* __restrict__ B,
    float* __restrict__ Cf, __hip_bfloat16* __restrict__ Cb,
    const float* __restrict__ bias, const float* __restrict__ resid,
    int M, int N, int K, int do_gelu)
{
    __shared__ __align__(16) __hip_bfloat16 As[64][32];
    __shared__ __align__(16) __hip_bfloat16 Bs[2048]; // NT:[n][k]=64x32, NN:[k][n]=32x64

    int t = threadIdx.x;
    int n0 = blockIdx.x * 64, m0 = blockIdx.y * 64;
    int w = t >> 6, lane = t & 63, quad = lane >> 4, l16 = lane & 15;

    floatx4 acc[4];
#pragma unroll
    for (int i = 0; i < 4; i++) acc[i] = (floatx4){0.f, 0.f, 0.f, 0.f};

    int ar = t >> 2, ac = (t & 3) * 8;   // A staging: 64 rows x 32 cols, 8/thread

    for (int k0 = 0; k0 < K; k0 += 32) {
        // stage A (bf16, 16B vector copy)
        *(uint4*)&As[ar][ac] =
            *(const uint4*)(A + (size_t)(m0 + ar) * K + k0 + ac);

        // stage B (fp32 -> bf16)
        if (BNT) {
            const float* src = B + (size_t)(n0 + ar) * K + k0 + ac;
            float4 f0 = *(const float4*)(src);
            float4 f1 = *(const float4*)(src + 4);
            short8 pk;
            pk[0] = f2bs(f0.x); pk[1] = f2bs(f0.y); pk[2] = f2bs(f0.z); pk[3] = f2bs(f0.w);
            pk[4] = f2bs(f1.x); pk[5] = f2bs(f1.y); pk[6] = f2bs(f1.z); pk[7] = f2bs(f1.w);
            *(short8*)&Bs[ar * 32 + ac] = pk;
        } else {
            int br = t >> 3, bc = (t & 7) * 8;  // 32 rows x 64 cols
            const float* src = B + (size_t)(k0 + br) * N + n0 + bc;
            float4 f0 = *(const float4*)(src);
            float4 f1 = *(const float4*)(src + 4);
            short8 pk;
            pk[0] = f2bs(f0.x); pk[1] = f2bs(f0.y); pk[2] = f2bs(f0.z); pk[3] = f2bs(f0.w);
            pk[4] = f2bs(f1.x); pk[5] = f2bs(f1.y); pk[6] = f2bs(f1.z); pk[7] = f2bs(f1.w);
            *(short8*)&Bs[br * 64 + bc] = pk;
        }
        __syncthreads();

        short8 a = *(const short8*)&As[w * 16 + l16][quad * 8];
#pragma unroll
        for (int nt = 0; nt < 4; nt++) {
            short8 bfr;
            if (BNT) {
                bfr = *(const short8*)&Bs[(nt * 16 + l16) * 32 + quad * 8];
            } else {
#pragma unroll
                for (int j = 0; j < 8; j++)
                    bfr[j] = ((const short*)Bs)[(quad * 8 + j) * 64 + nt * 16 + l16];
            }
            acc[nt] = __builtin_amdgcn_mfma_f32_16x16x32_bf16(a, bfr, acc[nt], 0, 0, 0);
        }
        __syncthreads();
    }

    // epilogue: D row = w*16 + quad*4 + r, col = nt*16 + l16
#pragma unroll
    for (int nt = 0; nt < 4; nt++) {
        int gn = n0 + nt * 16 + l16;
        float bv = bias ? bias[gn] : 0.0f;
#pragma unroll
        for (int r = 0; r < 4; r++) {
            int gm = m0 + w * 16 + quad * 4 + r;
            float v = acc[nt][r] + bv;
            if (do_gelu) v = 0.5f * v * (1.0f + erff(v * 0.70710678118654752f));
            if (resid) v += resid[(size_t)gm * N + gn];
            if (Cf) Cf[(size_t)gm * N + gn] = v;
            else    Cb[(size_t)gm * N + gn] = __float2bfloat16(v);
        }
    }
}

// ---------------------------------------------------------------- attention
// One wave per (b, h, qrow). lane = head dim (HD=64). Online softmax.
__global__ __launch_bounds__(256) void attn_kernel(
    const float* __restrict__ qkv, __hip_bfloat16* __restrict__ y)
{
    int wid = blockIdx.x * 4 + (threadIdx.x >> 6);  // (b*H + h)*T + q
    int lane = threadIdx.x & 63;
    int qrow = wid & (TSEQ - 1);
    int bh = wid >> 10;
    int h = bh & (HEADS - 1);
    int b = bh >> 4;

    const float scale = 0.125f;  // 1/sqrt(64)
    size_t rowbase = (size_t)b * TSEQ * (3 * CDIM);
    float qd = qkv[rowbase + (size_t)qrow * (3 * CDIM) + h * HDIM + lane] * scale;
    const float* kbase = qkv + rowbase + CDIM + h * HDIM + lane;
    const float* vbase = qkv + rowbase + 2 * CDIM + h * HDIM + lane;

    float m = -1e30f, l = 0.0f, o = 0.0f;
    for (int kk = 0; kk <= qrow; ++kk) {
        float s = qd * kbase[(size_t)kk * (3 * CDIM)];
        for (int off = 32; off; off >>= 1) s += __shfl_xor(s, off);
        float mn = fmaxf(m, s);
        float corr = __expf(m - mn);
        float pexp = __expf(s - mn);
        l = l * corr + pexp;
        o = o * corr + pexp * vbase[(size_t)kk * (3 * CDIM)];
        m = mn;
    }
    y[((size_t)(b * TSEQ + qrow)) * CDIM + h * HDIM + lane] =
        __float2bfloat16(o / l);
}

// ---------------------------------------------------------------- loss
__global__ __launch_bounds__(256) void loss_rows_kernel(
    const float* __restrict__ logits, const int* __restrict__ targets,
    float* __restrict__ out)
{
    int r = blockIdx.x, t = threadIdx.x;
    const float* row = logits + (size_t)r * VOCAB;
    __shared__ float red[4];
    int w = t >> 6, lane = t & 63;

    float mx = -1e30f;
    for (int c = t; c < VOCAB; c += 256) mx = fmaxf(mx, row[c]);
    for (int off = 32; off; off >>= 1) mx = fmaxf(mx, __shfl_xor(mx, off));
    if (lane == 0) red[w] = mx;
    __syncthreads();
    mx = fmaxf(fmaxf(red[0], red[1]), fmaxf(red[2], red[3]));

    float s = 0.0f;
    for (int c = t; c < VOCAB; c += 256) s += __expf(row[c] - mx);
    for (int off = 32; off; off >>= 1) s += __shfl_xor(s, off);
    __syncthreads();
    if (lane == 0) red[w] = s;
    __syncthreads();
    s = red[0] + red[1] + red[2] + red[3];

    if (t == 0) out[r] = logf(s) + mx - row[targets[r]];
}

__global__ __launch_bounds__(256) void loss_final_kernel(
    const float* __restrict__ lr, float* __restrict__ out)
{
    int t = threadIdx.x;
    float s = 0.0f;
    for (int c = t; c < ROWS; c += 256) s += lr[c];
    for (int off = 32; off; off >>= 1) s += __shfl_xor(s, off);
    __shared__ float red[4];
    int w = t >> 6, lane = t & 63;
    if (lane == 0) red[w] = s;
    __syncthreads();
    if (t == 0) out[0] = (red[0] + red[1] + red[2] + red[3]) * (1.0f / ROWS);
}

// ---------------------------------------------------------------- launch
extern "C" void kernel_launch(void* const* d_in, const int* in_sizes, int n_in,
                              void* d_out, int out_size, void* d_ws, size_t ws_size,
                              hipStream_t stream)
{
    const int*   idx     = (const int*)d_in[0];
    const int*   targets = (const int*)d_in[1];
    const float* wte     = (const float*)d_in[2];
    const float* wpe     = (const float*)d_in[3];
    const float* ln1_g   = (const float*)d_in[4];
    const float* ln1_b   = (const float*)d_in[5];
    const float* qkv_w   = (const float*)d_in[6];
    const float* aproj_w = (const float*)d_in[7];
    const float* ln2_g   = (const float*)d_in[8];
    const float* ln2_b   = (const float*)d_in[9];
    const float* fc_w    = (const float*)d_in[10];
    const float* fc_b    = (const float*)d_in[11];
    const float* mproj_w = (const float*)d_in[12];
    const float* mproj_b = (const float*)d_in[13];
    const float* lnf_g   = (const float*)d_in[14];
    const float* lnf_b   = (const float*)d_in[15];

    char* p = (char*)d_ws;
    float* x            = (float*)p;            p += (size_t)ROWS * CDIM * 4;
    float* qkv          = (float*)p;            p += (size_t)ROWS * 3 * CDIM * 4;
    __hip_bfloat16* h_bf = (__hip_bfloat16*)p;  p += (size_t)ROWS * CDIM * 2;
    __hip_bfloat16* g_bf = (__hip_bfloat16*)p;  p += (size_t)ROWS * DFFDIM * 2;
    __hip_bfloat16* y_bf = (__hip_bfloat16*)p;  p += (size_t)ROWS * CDIM * 2;
    float* lrow         = (float*)p;            p += (size_t)ROWS * 4;

    float* logits = (float*)d_out;

    embed_kernel<<<ROWS, 256, 0, stream>>>(idx, wte, wpe, x);

    for (int l = 0; l < NLAYERS; l++) {
        ln_kernel<<<ROWS, 256, 0, stream>>>(x, ln1_g + l * CDIM, ln1_b + l * CDIM, h_bf);
        gemm_kernel<false><<<dim3(3 * CDIM / 64, ROWS / 64), 256, 0, stream>>>(
            h_bf, qkv_w + (size_t)l * CDIM * 3 * CDIM, qkv, nullptr,
            nullptr, nullptr, ROWS, 3 * CDIM, CDIM, 0);
        attn_kernel<<<ROWS * HEADS / 4, 256, 0, stream>>>(qkv, y_bf);
        gemm_kernel<false><<<dim3(CDIM / 64, ROWS / 64), 256, 0, stream>>>(
            y_bf, aproj_w + (size_t)l * CDIM * CDIM, x, nullptr,
            nullptr, x, ROWS, CDIM, CDIM, 0);
        ln_kernel<<<ROWS, 256, 0, stream>>>(x, ln2_g + l * CDIM, ln2_b + l * CDIM, h_bf);
        gemm_kernel<false><<<dim3(DFFDIM / 64, ROWS / 64), 256, 0, stream>>>(
            h_bf, fc_w + (size_t)l * CDIM * DFFDIM, nullptr, g_bf,
            fc_b + l * DFFDIM, nullptr, ROWS, DFFDIM, CDIM, 1);
        gemm_kernel<false><<<dim3(CDIM / 64, ROWS / 64), 256, 0, stream>>>(
            g_bf, mproj_w + (size_t)l * DFFDIM * CDIM, x, nullptr,
            mproj_b + l * CDIM, x, ROWS, CDIM, DFFDIM, 0);
    }

    ln_kernel<<<ROWS, 256, 0, stream>>>(x, lnf_g, lnf_b, h_bf);
    gemm_kernel<true><<<dim3(VOCAB / 64, ROWS / 64), 256, 0, stream>>>(
        h_bf, wte, logits, nullptr, nullptr, nullptr, ROWS, VOCAB, CDIM, 0);

    loss_rows_kernel<<<ROWS, 256, 0, stream>>>(logits, targets, lrow);
    loss_final_kernel<<<1, 256, 0, stream>>>(lrow, logits + (size_t)ROWS * VOCAB);
}